// Round 2
// baseline (8963.311 us; speedup 1.0000x reference)
//
#include <hip/hip_runtime.h>

// ---------------------------------------------------------------------------
// Problem constants
// ---------------------------------------------------------------------------
#define Bv 8
#define Sv 256
#define HIDv 1024
#define Hv 16
#define Dv 64
#define Fv 64
#define LR 0.1f
#define SCALE (2.0f / 8192.0f)   // dLoss/dpred scale: 2/(B*H*D)

using bf16x8 = __attribute__((ext_vector_type(8))) short;
using f32x4  = __attribute__((ext_vector_type(4))) float;
#define MFMA16(A, B, C) __builtin_amdgcn_mfma_f32_16x16x32_bf16(A, B, C, 0, 0, 0)

constexpr int PITCH = 68;  // 68 floats = 272 B row pitch: 16B-aligned, conflict-light

// LDS layout (floats)
constexpr int OW1 = 0;
constexpr int OW2 = 64 * PITCH;
constexpr int OLW = 2 * 64 * PITCH;
constexpr int OKS = 3 * 64 * PITCH;       // k_s   [16][68]
constexpr int OHS = OKS + 16 * PITCH;     // h_s   [16][68]
constexpr int OZS = OHS + 16 * PITCH;     // z_s   [16][68]
constexpr int ODP = OZS + 16 * PITCH;     // dpred [16][68]
constexpr int ODO = ODP + 16 * PITCH;     // do    [16][68]
constexpr int ODA = ODO + 16 * PITCH;     // da1   [8][68]
constexpr int OOS = ODA + 8 * PITCH;      // o     [8][68]
constexpr int ODZ = OOS + 8 * PITCH;      // dz    [8][68]
constexpr int OXH = ODZ + 8 * PITCH;      // xhat  [8][68]
constexpr int OGD = OXH + 8 * PITCH;      // gelu' [8][68]
constexpr int OTG = OGD + 8 * PITCH;      // tgt   [8][68]
constexpr int OVB1 = OTG + 8 * PITCH;     // b1[64]
constexpr int OVB2 = OVB1 + 64;
constexpr int OVLG = OVB2 + 64;
constexpr int OVLB = OVLG + 64;
constexpr int OVLOSSB = OVLB + 64;
constexpr int OVTG = OVLOSSB + 64;
constexpr int OVTB = OVTG + 64;
constexpr int ORSTD = OVTB + 64;
constexpr int LDS_TOTAL = ORSTD + 8;      // 22216 floats = 88864 B

// ---------------------------------------------------------------------------
// Helpers
// ---------------------------------------------------------------------------
__device__ __forceinline__ short bf_rn(float v) {
    unsigned u = __float_as_uint(v);
    unsigned r = u + 0x7fffu + ((u >> 16) & 1u);   // round-to-nearest-even
    return (short)(r >> 16);
}

__device__ __forceinline__ void cvt1(float v, short &hi, short &lo) {
    hi = bf_rn(v);
    float hf = __uint_as_float(((unsigned)(unsigned short)hi) << 16);
    lo = bf_rn(v - hf);
}

__device__ __forceinline__ void cvt8(float4 a, float4 b, bf16x8 &hi, bf16x8 &lo) {
    float v[8] = {a.x, a.y, a.z, a.w, b.x, b.y, b.z, b.w};
#pragma unroll
    for (int j = 0; j < 8; ++j) {
        short h, l;
        cvt1(v[j], h, l);
        hi[j] = h; lo[j] = l;
    }
}

__device__ __forceinline__ float red32(float v) {
    v += __shfl_xor(v, 1);
    v += __shfl_xor(v, 2);
    v += __shfl_xor(v, 4);
    v += __shfl_xor(v, 8);
    v += __shfl_xor(v, 16);
    return v;
}

__device__ __forceinline__ void gelu_both(float x, float &g, float &dg) {
    const float C0 = 0.7978845608028654f, A0 = 0.044715f;
    float x2 = x * x;
    float u = C0 * x * (1.0f + A0 * x2);
    float t = tanhf(u);
    g = 0.5f * x * (1.0f + t);
    float du = C0 * (1.0f + 3.0f * A0 * x2);
    dg = 0.5f * (1.0f + t) + 0.5f * x * (1.0f - t * t) * du;
}

__device__ __forceinline__ float gelu_f(float x) {
    const float C0 = 0.7978845608028654f, A0 = 0.044715f;
    float u = C0 * x * (1.0f + A0 * x * x);
    return 0.5f * x * (1.0f + tanhf(u));
}

// M=16 (B rows, padded), K=64, N=64 (wave w owns nt=w tile).
__device__ __forceinline__ f32x4 mmA(const float *Ast, const float *Wst,
                                     int w, int c, int q) {
    f32x4 acc = {0.f, 0.f, 0.f, 0.f};
#pragma unroll
    for (int kt = 0; kt < 2; ++kt) {
        const float *ap = Ast + c * PITCH + 32 * kt + 8 * q;
        float4 a0 = *(const float4 *)ap;
        float4 a1 = *(const float4 *)(ap + 4);
        bf16x8 ahi, alo;
        cvt8(a0, a1, ahi, alo);
        bf16x8 bhi, blo;
#pragma unroll
        for (int j = 0; j < 8; ++j) {
            float bv = Wst[(32 * kt + 8 * q + j) * PITCH + 16 * w + c];
            short h, l;
            cvt1(bv, h, l);
            bhi[j] = h; blo[j] = l;
        }
        acc = MFMA16(ahi, bhi, acc);
        acc = MFMA16(alo, bhi, acc);
        acc = MFMA16(ahi, blo, acc);
        acc = MFMA16(alo, blo, acc);
    }
    return acc;
}

// Transposed form: out(64x16) tile mt=w of  Wst(64x64) @ stage^T.
__device__ __forceinline__ f32x4 mmT(const float *Wst, const float *Ast,
                                     int w, int c, int q) {
    f32x4 acc = {0.f, 0.f, 0.f, 0.f};
#pragma unroll
    for (int kt = 0; kt < 2; ++kt) {
        const float *ap = Wst + (16 * w + c) * PITCH + 32 * kt + 8 * q;
        float4 a0 = *(const float4 *)ap;
        float4 a1 = *(const float4 *)(ap + 4);
        bf16x8 ahi, alo;
        cvt8(a0, a1, ahi, alo);
        const float *bp = Ast + c * PITCH + 32 * kt + 8 * q;
        float4 b0 = *(const float4 *)bp;
        float4 b1 = *(const float4 *)(bp + 4);
        bf16x8 bhi, blo;
        cvt8(b0, b1, bhi, blo);
        acc = MFMA16(ahi, bhi, acc);
        acc = MFMA16(alo, bhi, acc);
        acc = MFMA16(ahi, blo, acc);
        acc = MFMA16(alo, blo, acc);
    }
    return acc;
}

// dW = X^T @ Y (K = 8 real, padded to 32), output 64x64, wave w owns nt=w.
// RMW: W -= LR * dW
__device__ __forceinline__ void mmW(const float *Xst, const float *Yst,
                                    float *Wout, int w, int c, int q) {
    bf16x8 bhi, blo;
#pragma unroll
    for (int j = 0; j < 8; ++j) {
        float bv = (q == 0) ? Yst[j * PITCH + 16 * w + c] : 0.f;
        short h, l;
        cvt1(bv, h, l);
        bhi[j] = h; blo[j] = l;
    }
#pragma unroll
    for (int mt = 0; mt < 4; ++mt) {
        bf16x8 ahi, alo;
#pragma unroll
        for (int j = 0; j < 8; ++j) {
            float av = (q == 0) ? Xst[j * PITCH + 16 * mt + c] : 0.f;
            short h, l;
            cvt1(av, h, l);
            ahi[j] = h; alo[j] = l;
        }
        f32x4 acc = {0.f, 0.f, 0.f, 0.f};
        acc = MFMA16(ahi, bhi, acc);
        acc = MFMA16(alo, bhi, acc);
        acc = MFMA16(ahi, blo, acc);
        acc = MFMA16(alo, blo, acc);
#pragma unroll
        for (int r = 0; r < 4; ++r)
            Wout[(16 * mt + 4 * q + r) * PITCH + 16 * w + c] -= LR * acc[r];
    }
}

// ---------------------------------------------------------------------------
// TTT scan kernel: one block (256 thr = 4 waves) per head
// ---------------------------------------------------------------------------
__global__ __launch_bounds__(256) void ttt_scan(
    const float *__restrict__ q_g, const float *__restrict__ k_g,
    const float *__restrict__ v_g, float *__restrict__ out_g,
    const float *__restrict__ fw_w1, const float *__restrict__ fw_b1,
    const float *__restrict__ fw_w2, const float *__restrict__ fw_b2,
    const float *__restrict__ fw_lng, const float *__restrict__ fw_lnb,
    const float *__restrict__ loss_w, const float *__restrict__ loss_bv,
    const float *__restrict__ ttt_gv, const float *__restrict__ ttt_bv) {
    extern __shared__ float lds[];
    const int h = blockIdx.x;
    const int tid = threadIdx.x;
    const int w = tid >> 6, lane = tid & 63, c = lane & 15, q = lane >> 4;

    float *W1 = lds + OW1, *W2 = lds + OW2, *Lw = lds + OLW;
    float *k_s = lds + OKS, *h_s = lds + OHS, *z_s = lds + OZS;
    float *dp_s = lds + ODP, *do_s = lds + ODO, *da_s = lds + ODA;
    float *o_s = lds + OOS, *dz_s = lds + ODZ, *xh_s = lds + OXH;
    float *gd_s = lds + OGD, *tg_s = lds + OTG;
    float *b1_s = lds + OVB1, *b2_s = lds + OVB2, *lg_s = lds + OVLG;
    float *lb_s = lds + OVLB, *Lb_s = lds + OVLOSSB;
    float *tG_s = lds + OVTG, *tB_s = lds + OVTB, *rstd_s = lds + ORSTD;

    // ---- init LDS
    for (int i = tid; i < 4096; i += 256) {
        int r = i >> 6, cc = i & 63;
        W1[r * PITCH + cc] = fw_w1[h * 4096 + i];   // [d][f]
        W2[r * PITCH + cc] = fw_w2[h * 4096 + i];   // [f][d]
        Lw[r * PITCH + cc] = loss_w[i];             // [d][e]
    }
    for (int i = tid; i < (LDS_TOTAL - OKS); i += 256) k_s[i] = 0.f;
    __syncthreads();   // CRITICAL: zero-fill must complete before param writes
    if (tid < 64) {
        b1_s[tid] = fw_b1[h * 64 + tid];
        b2_s[tid] = fw_b2[h * 64 + tid];
        lg_s[tid] = fw_lng[h * 64 + tid];
        lb_s[tid] = fw_lnb[h * 64 + tid];
        Lb_s[tid] = loss_bv[tid];
        tG_s[tid] = ttt_gv[h * 64 + tid];
        tB_s[tid] = ttt_bv[h * 64 + tid];
    }
    __syncthreads();

    const int bb = tid >> 5;          // batch row 0..7
    const int j0 = (tid & 31) * 2;    // column pair

#pragma unroll 1
    for (int t = 0; t < Sv; ++t) {
        // ---- token prologue: load k, target = v - k
        {
            int idx = ((bb * Sv + t) * Hv + h) * Dv + j0;
            float2 kv = *(const float2 *)&k_g[idx];
            float2 vv = *(const float2 *)&v_g[idx];
            k_s[bb * PITCH + j0] = kv.x;
            k_s[bb * PITCH + j0 + 1] = kv.y;
            tg_s[bb * PITCH + j0] = vv.x - kv.x;
            tg_s[bb * PITCH + j0 + 1] = vv.y - kv.y;
        }
        __syncthreads();

#pragma unroll 1
        for (int step = 0; step < 4; ++step) {
            // F1: a1 = k@W1 + b1 ; h = gelu(a1); stage h, gelu'
            f32x4 acc = mmA(k_s, W1, w, c, q);
            {
                float bias = b1_s[16 * w + c];
                if (q < 2) {
#pragma unroll
                    for (int r = 0; r < 4; ++r) {
                        float g, dg;
                        gelu_both(acc[r] + bias, g, dg);
                        int row = 4 * q + r;
                        h_s[row * PITCH + 16 * w + c] = g;
                        gd_s[row * PITCH + 16 * w + c] = dg;
                    }
                }
            }
            __syncthreads();
            // F2: o = h@W2 + b2
            acc = mmA(h_s, W2, w, c, q);
            {
                float bias = b2_s[16 * w + c];
                if (q < 2) {
#pragma unroll
                    for (int r = 0; r < 4; ++r)
                        o_s[(4 * q + r) * PITCH + 16 * w + c] = acc[r] + bias;
                }
            }
            __syncthreads();
            // LN fwd (thread-mapped)
            {
                float x0 = o_s[bb * PITCH + j0], x1 = o_s[bb * PITCH + j0 + 1];
                float mu = red32(x0 + x1) * (1.f / 64.f);
                float d0 = x0 - mu, d1 = x1 - mu;
                float var = red32(d0 * d0 + d1 * d1) * (1.f / 64.f);
                float rs = rsqrtf(var + 1e-5f);
                float xh0 = d0 * rs, xh1 = d1 * rs;
                z_s[bb * PITCH + j0] = xh0 * lg_s[j0] + lb_s[j0];
                z_s[bb * PITCH + j0 + 1] = xh1 * lg_s[j0 + 1] + lb_s[j0 + 1];
                xh_s[bb * PITCH + j0] = xh0;
                xh_s[bb * PITCH + j0 + 1] = xh1;
                if ((tid & 31) == 0) rstd_s[bb] = rs;
            }
            __syncthreads();
            // F3: pred = z@Lw + Lb ; dpred = (pred - tgt)*scale
            acc = mmA(z_s, Lw, w, c, q);
            if (q < 2) {
#pragma unroll
                for (int r = 0; r < 4; ++r) {
                    int row = 4 * q + r, col = 16 * w + c;
                    dp_s[row * PITCH + col] =
                        (acc[r] + Lb_s[col] - tg_s[row * PITCH + col]) * SCALE;
                }
            }
            __syncthreads();
            // B1: dz^T = Lw @ dpred^T  (tile mt=w) -> dz_s (transposed write)
            acc = mmT(Lw, dp_s, w, c, q);
            if (c < 8) {
#pragma unroll
                for (int r = 0; r < 4; ++r)
                    dz_s[c * PITCH + 16 * w + 4 * q + r] = acc[r];
            }
            __syncthreads();
            // LN bwd (thread-mapped)
            {
                float dz0 = dz_s[bb * PITCH + j0], dz1 = dz_s[bb * PITCH + j0 + 1];
                float xh0 = xh_s[bb * PITCH + j0], xh1 = xh_s[bb * PITCH + j0 + 1];
                float dxh0 = dz0 * lg_s[j0], dxh1 = dz1 * lg_s[j0 + 1];
                float S1 = red32(dxh0 + dxh1) * (1.f / 64.f);
                float S2 = red32(dxh0 * xh0 + dxh1 * xh1) * (1.f / 64.f);
                float rs = rstd_s[bb];
                do_s[bb * PITCH + j0] = rs * (dxh0 - S1 - xh0 * S2);
                do_s[bb * PITCH + j0 + 1] = rs * (dxh1 - S1 - xh1 * S2);
            }
            __syncthreads();
            // B2: dh^T = W2 @ do^T ; da1^T = dh^T * gelu'^T -> da_s
            acc = mmT(W2, do_s, w, c, q);
            if (c < 8) {
#pragma unroll
                for (int r = 0; r < 4; ++r) {
                    int f = 16 * w + 4 * q + r;
                    da_s[c * PITCH + f] = acc[r] * gd_s[c * PITCH + f];
                }
            }
            __syncthreads();
            // dW2 = h^T@do ; dW1 = k^T@da1 ; vector params
            mmW(h_s, do_s, W2, w, c, q);
            mmW(k_s, da_s, W1, w, c, q);
            if (tid < 64) {
                float dlb = 0.f, dlg = 0.f, db2 = 0.f, db1 = 0.f;
#pragma unroll
                for (int b = 0; b < 8; ++b) {
                    float dzv = dz_s[b * PITCH + tid];
                    dlb += dzv;
                    dlg += dzv * xh_s[b * PITCH + tid];
                    db2 += do_s[b * PITCH + tid];
                    db1 += da_s[b * PITCH + tid];
                }
                lb_s[tid] -= LR * dlb;
                lg_s[tid] -= LR * dlg;
                b2_s[tid] -= LR * db2;
                b1_s[tid] -= LR * db1;
            }
            __syncthreads();
        }

        // ---- final forward with updated params
        f32x4 acc = mmA(k_s, W1, w, c, q);
        {
            float bias = b1_s[16 * w + c];
            if (q < 2) {
#pragma unroll
                for (int r = 0; r < 4; ++r) {
                    float g, dg;
                    gelu_both(acc[r] + bias, g, dg);
                    h_s[(4 * q + r) * PITCH + 16 * w + c] = g;
                }
            }
        }
        __syncthreads();
        acc = mmA(h_s, W2, w, c, q);
        {
            float bias = b2_s[16 * w + c];
            if (q < 2) {
#pragma unroll
                for (int r = 0; r < 4; ++r)
                    o_s[(4 * q + r) * PITCH + 16 * w + c] = acc[r] + bias;
            }
        }
        __syncthreads();
        {
            float x0 = o_s[bb * PITCH + j0], x1 = o_s[bb * PITCH + j0 + 1];
            float mu = red32(x0 + x1) * (1.f / 64.f);
            float d0 = x0 - mu, d1 = x1 - mu;
            float var = red32(d0 * d0 + d1 * d1) * (1.f / 64.f);
            float rs = rsqrtf(var + 1e-5f);
            float z0 = d0 * rs * lg_s[j0] + lb_s[j0];
            float z1 = d1 * rs * lg_s[j0 + 1] + lb_s[j0 + 1];
            // second LN with ttt_g/ttt_b
            float mu2 = red32(z0 + z1) * (1.f / 64.f);
            float e0 = z0 - mu2, e1 = z1 - mu2;
            float var2 = red32(e0 * e0 + e1 * e1) * (1.f / 64.f);
            float rs2 = rsqrtf(var2 + 1e-5f);
            float z20 = e0 * rs2 * tG_s[j0] + tB_s[j0];
            float z21 = e1 * rs2 * tG_s[j0 + 1] + tB_s[j0 + 1];
            int idx = ((bb * Sv + t) * Hv + h) * Dv + j0;
            float2 qv = *(const float2 *)&q_g[idx];
            float2 ov;
            ov.x = qv.x + z20;
            ov.y = qv.y + z21;
            *(float2 *)&out_g[idx] = ov;
        }
        __syncthreads();
    }
}

// ---------------------------------------------------------------------------
// fp32 GEMM: C[M,N] = A[M,K] @ B[K,N]; mode 1: C = gelu(acc) * gate_ln
// 64x64 tile, BK=16, 256 threads, 4x4 micro-tile
// ---------------------------------------------------------------------------
__global__ __launch_bounds__(256) void gemm_f32(
    const float *__restrict__ A, const float *__restrict__ B,
    float *__restrict__ C, const float *__restrict__ gate_ln,
    int M, int N, int K, int mode) {
    __shared__ float As[16][68];
    __shared__ float Bs[16][64];
    const int tid = threadIdx.x;
    const int tx = tid & 15, ty = tid >> 4;
    const int bm = blockIdx.y * 64, bn = blockIdx.x * 64;

    float acc[4][4] = {};
    for (int k0 = 0; k0 < K; k0 += 16) {
        {
            int r = tid >> 2, kk = (tid & 3) * 4;
            float4 av = *(const float4 *)(A + (long)(bm + r) * K + k0 + kk);
            As[kk + 0][r] = av.x;
            As[kk + 1][r] = av.y;
            As[kk + 2][r] = av.z;
            As[kk + 3][r] = av.w;
            int rr = tid >> 4, cc = (tid & 15) * 4;
            float4 bv = *(const float4 *)(B + (long)(k0 + rr) * N + bn + cc);
            *(float4 *)&Bs[rr][cc] = bv;
        }
        __syncthreads();
#pragma unroll
        for (int kk = 0; kk < 16; ++kk) {
            float4 a4 = *(float4 *)&As[kk][ty * 4];
            float4 b4 = *(float4 *)&Bs[kk][tx * 4];
            float a[4] = {a4.x, a4.y, a4.z, a4.w};
            float b[4] = {b4.x, b4.y, b4.z, b4.w};
#pragma unroll
            for (int i = 0; i < 4; ++i)
#pragma unroll
                for (int j = 0; j < 4; ++j) acc[i][j] += a[i] * b[j];
        }
        __syncthreads();
    }
#pragma unroll
    for (int i = 0; i < 4; ++i) {
        int row = bm + ty * 4 + i;
        float4 out;
        float v[4];
#pragma unroll
        for (int j = 0; j < 4; ++j) {
            float val = acc[i][j];
            if (mode == 1) {
                int col = bn + tx * 4 + j;
                val = gelu_f(val) * gate_ln[(long)row * N + col];
            }
            v[j] = val;
        }
        out.x = v[0]; out.y = v[1]; out.z = v[2]; out.w = v[3];
        *(float4 *)(C + (long)row * N + bn + tx * 4) = out;
    }
}

// ---------------------------------------------------------------------------
// Row LayerNorm over 1024 (post-scan, pn_g / pn_b)
// ---------------------------------------------------------------------------
__global__ __launch_bounds__(256) void row_ln(const float *__restrict__ in,
                                              float *__restrict__ out,
                                              const float *__restrict__ g,
                                              const float *__restrict__ b) {
    __shared__ float sred[4], s2red[4];
    const int row = blockIdx.x;
    const int tid = threadIdx.x;
    const float *x = in + (long)row * 1024;
    float4 v = *(const float4 *)(x + tid * 4);
    float s = v.x + v.y + v.z + v.w;
    float s2 = v.x * v.x + v.y * v.y + v.z * v.z + v.w * v.w;
#pragma unroll
    for (int m = 1; m <= 32; m <<= 1) {
        s += __shfl_xor(s, m);
        s2 += __shfl_xor(s2, m);
    }
    if ((tid & 63) == 0) {
        sred[tid >> 6] = s;
        s2red[tid >> 6] = s2;
    }
    __syncthreads();
    float S = sred[0] + sred[1] + sred[2] + sred[3];
    float S2 = s2red[0] + s2red[1] + s2red[2] + s2red[3];
    float mu = S * (1.f / 1024.f);
    float var = S2 * (1.f / 1024.f) - mu * mu;
    float rs = rsqrtf(var + 1e-5f);
    float o[4] = {v.x, v.y, v.z, v.w};
    float4 ov;
    float r[4];
#pragma unroll
    for (int i = 0; i < 4; ++i) {
        int col = tid * 4 + i;
        r[i] = (o[i] - mu) * rs * g[col] + b[col];
    }
    ov.x = r[0]; ov.y = r[1]; ov.z = r[2]; ov.w = r[3];
    *(float4 *)(out + (long)row * 1024 + tid * 4) = ov;
}

// ---------------------------------------------------------------------------
// Launch
// ---------------------------------------------------------------------------
extern "C" void kernel_launch(void *const *d_in, const int *in_sizes, int n_in,
                              void *d_out, int out_size, void *d_ws,
                              size_t ws_size, hipStream_t stream) {
    const float *x = (const float *)d_in[0];
    const float *wq = (const float *)d_in[1];
    const float *wk = (const float *)d_in[2];
    const float *wv = (const float *)d_in[3];
    const float *fw_w1 = (const float *)d_in[4];
    const float *fw_b1 = (const float *)d_in[5];
    const float *fw_w2 = (const float *)d_in[6];
    const float *fw_b2 = (const float *)d_in[7];
    const float *fw_lng = (const float *)d_in[8];
    const float *fw_lnb = (const float *)d_in[9];
    const float *loss_w = (const float *)d_in[10];
    const float *loss_b = (const float *)d_in[11];
    const float *ttt_g = (const float *)d_in[12];
    const float *ttt_b = (const float *)d_in[13];
    const float *wo = (const float *)d_in[14];
    const float *wg = (const float *)d_in[15];
    const float *pn_g = (const float *)d_in[16];
    const float *pn_b = (const float *)d_in[17];

    const long MAT = 2048L * 1024L;
    float *q_ws = (float *)d_ws;
    float *k_ws = q_ws + MAT;
    float *v_ws = k_ws + MAT;
    float *out_ws = v_ws + MAT;
    // post-scan phases reuse k/v buffers (k,v dead after the scan)
    float *ln_ws = k_ws;
    float *gated_ws = v_ws;

    dim3 gg(1024 / 64, 2048 / 64), bt(256);
    // q, k, v projections
    hipLaunchKernelGGL(gemm_f32, gg, bt, 0, stream, x, wq, q_ws,
                       (const float *)nullptr, 2048, 1024, 1024, 0);
    hipLaunchKernelGGL(gemm_f32, gg, bt, 0, stream, x, wk, k_ws,
                       (const float *)nullptr, 2048, 1024, 1024, 0);
    hipLaunchKernelGGL(gemm_f32, gg, bt, 0, stream, x, wv, v_ws,
                       (const float *)nullptr, 2048, 1024, 1024, 0);

    // sequential TTT scan, one block per head
    (void)hipFuncSetAttribute((const void *)ttt_scan,
                              hipFuncAttributeMaxDynamicSharedMemorySize,
                              LDS_TOTAL * 4);
    hipLaunchKernelGGL(ttt_scan, dim3(16), dim3(256), LDS_TOTAL * 4, stream,
                       q_ws, k_ws, v_ws, out_ws, fw_w1, fw_b1, fw_w2, fw_b2,
                       fw_lng, fw_lnb, loss_w, loss_b, ttt_g, ttt_b);

    // post: LN(out), gated = gelu(x@wg)*ln, y = gated@wo
    hipLaunchKernelGGL(row_ln, dim3(2048), dim3(256), 0, stream, out_ws, ln_ws,
                       pn_g, pn_b);
    hipLaunchKernelGGL(gemm_f32, gg, bt, 0, stream, x, wg, gated_ws, ln_ws,
                       2048, 1024, 1024, 1);
    hipLaunchKernelGGL(gemm_f32, gg, bt, 0, stream, gated_ws, wo,
                       (float *)d_out, (const float *)nullptr, 2048, 1024,
                       1024, 0);
}

// Round 3
// 6192.545 us; speedup vs baseline: 1.4474x; 1.4474x over previous
//
#include <hip/hip_runtime.h>

// ---------------------------------------------------------------------------
// Problem constants
// ---------------------------------------------------------------------------
#define Bv 8
#define Sv 256
#define Hv 16
#define Dv 64
#define LR 0.1f
#define SCALE (2.0f / 8192.0f)   // dLoss/dpred scale: 2/(B*H*D)

using bf16x8 = __attribute__((ext_vector_type(8))) short;
using bf16x4 = __attribute__((ext_vector_type(4))) short;
using f32x4  = __attribute__((ext_vector_type(4))) float;
#define MFMA16(A, B, C) __builtin_amdgcn_mfma_f32_16x16x32_bf16(A, B, C, 0, 0, 0)

// ---------------------------------------------------------------------------
// LDS layout (ushort units for bf16 planes, float units for fp32 areas)
// Weight/row planes: pitch 136 ushort = 272 B (hi[64] | lo[64] | pad[8]).
// T arrays: pitch 16 ushort = 32 B (hi[8] | lo[8]).
// ---------------------------------------------------------------------------
constexpr int U_W1T = 0;          // [f][d] planes, 64x136
constexpr int U_W2T = 8704;      // [d][f]
constexpr int U_W2R = 17408;     // [f][d]
constexpr int U_LwT = 26112;     // [e][d]
constexpr int U_LwR = 34816;     // [d][e]
constexpr int U_K   = 43520;     // [b pad16][d] 16x136
constexpr int U_H   = 45696;     // [b][f]
constexpr int U_Z   = 47872;     // [b][d]
constexpr int U_DP  = 50048;     // [b][e]
constexpr int U_DO  = 52224;     // [b][d]
constexpr int U_KT  = 54400;     // [d][b] 64x16
constexpr int U_HT  = 55424;     // [f][b]
constexpr int U_DOT = 56448;     // [d][b]
constexpr int U_DAT = 57472;     // [f][b]
constexpr int F_BASE = 29248;    // = 58496/2
constexpr int F_O   = F_BASE;        // o / dz shared, [8][68]
constexpr int F_XH  = F_BASE + 544;
constexpr int F_GD  = F_BASE + 1088;
constexpr int F_TG  = F_BASE + 1632;
constexpr int F_B1  = F_BASE + 2176;
constexpr int F_B2  = F_B1 + 64;
constexpr int F_LG  = F_B2 + 64;
constexpr int F_LB  = F_LG + 64;
constexpr int F_LBV = F_LB + 64;
constexpr int F_TGm = F_LBV + 64;
constexpr int F_TBm = F_TGm + 64;
constexpr int F_RSTD = F_TBm + 64;
constexpr int LDS_BYTES = (F_RSTD + 8) * 4;   // 127520 B

// ---------------------------------------------------------------------------
// Helpers
// ---------------------------------------------------------------------------
__device__ __forceinline__ short bf_rn(float v) {
    unsigned u = __float_as_uint(v);
    unsigned r = u + 0x7fffu + ((u >> 16) & 1u);   // round-to-nearest-even
    return (short)(r >> 16);
}
__device__ __forceinline__ void cvt1(float v, short &hi, short &lo) {
    hi = bf_rn(v);
    float hf = __uint_as_float(((unsigned)(unsigned short)hi) << 16);
    lo = bf_rn(v - hf);
}
__device__ __forceinline__ float bf2f(short u) {
    return __uint_as_float(((unsigned)(unsigned short)u) << 16);
}
__device__ __forceinline__ unsigned pack2(short a, short b) {
    return ((unsigned)(unsigned short)a) | (((unsigned)(unsigned short)b) << 16);
}
__device__ __forceinline__ float red32(float v) {
    v += __shfl_xor(v, 1);
    v += __shfl_xor(v, 2);
    v += __shfl_xor(v, 4);
    v += __shfl_xor(v, 8);
    v += __shfl_xor(v, 16);
    return v;
}
__device__ __forceinline__ float fast_tanh(float u) {
    u = fminf(fmaxf(u, -10.f), 10.f);
    float e = __expf(2.0f * u);
    return (e - 1.0f) / (e + 1.0f);
}
__device__ __forceinline__ void gelu_both(float x, float &g, float &dg) {
    const float C0 = 0.7978845608028654f, A0 = 0.044715f;
    float x2 = x * x;
    float u = C0 * x * (1.0f + A0 * x2);
    float t = fast_tanh(u);
    g = 0.5f * x * (1.0f + t);
    float du = C0 * (1.0f + 3.0f * A0 * x2);
    dg = 0.5f * (1.0f + t) + 0.5f * x * (1.0f - t * t) * du;
}
__device__ __forceinline__ float gelu_f(float x) {
    const float C0 = 0.7978845608028654f, A0 = 0.044715f;
    float u = C0 * x * (1.0f + A0 * x * x);
    return 0.5f * x * (1.0f + fast_tanh(u));
}

// C[16x16 tile w] = A(16x64, row planes) @ B(64x64 via n-major planes)
// 4-MFMA split product (full hi/lo cross) for accuracy; two independent
// accumulation chains (kt) to halve MFMA dependency latency.
__device__ __forceinline__ f32x4 mm64(const unsigned short *Ap,
                                      const unsigned short *Bp,
                                      int w, int c, int q) {
    const unsigned short *ar = Ap + c * 136 + 8 * q;
    const unsigned short *br = Bp + (16 * w + c) * 136 + 8 * q;
    bf16x8 ah0 = *(const bf16x8 *)(ar);
    bf16x8 al0 = *(const bf16x8 *)(ar + 64);
    bf16x8 bh0 = *(const bf16x8 *)(br);
    bf16x8 bl0 = *(const bf16x8 *)(br + 64);
    bf16x8 ah1 = *(const bf16x8 *)(ar + 32);
    bf16x8 al1 = *(const bf16x8 *)(ar + 96);
    bf16x8 bh1 = *(const bf16x8 *)(br + 32);
    bf16x8 bl1 = *(const bf16x8 *)(br + 96);
    f32x4 x0 = {0.f, 0.f, 0.f, 0.f}, x1 = {0.f, 0.f, 0.f, 0.f};
    x0 = MFMA16(ah0, bh0, x0); x1 = MFMA16(ah1, bh1, x1);
    x0 = MFMA16(al0, bh0, x0); x1 = MFMA16(al1, bh1, x1);
    x0 = MFMA16(ah0, bl0, x0); x1 = MFMA16(ah1, bl1, x1);
    x0 = MFMA16(al0, bl0, x0); x1 = MFMA16(al1, bl1, x1);
    return x0 + x1;
}

// W(tile col n=16w+c) -= LR * X^T@Y ; X,Y given as T-arrays [64][b:8] bf16.
// WT planes: rows = n-index of this op's OUTPUT COLUMN owner (see callers).
// Optional WR scatter keeps the second orientation consistent.
__device__ __forceinline__ void updW(const unsigned short *XT,
                                     const unsigned short *YT,
                                     unsigned short *WT, unsigned short *WR,
                                     int w, int c, int q) {
    bf16x8 zf; 
#pragma unroll
    for (int j = 0; j < 8; ++j) zf[j] = 0;
    bf16x8 bh = zf, bl = zf;
    if (q == 0) {
        bh = *(const bf16x8 *)&YT[(16 * w + c) * 16];
        bl = *(const bf16x8 *)&YT[(16 * w + c) * 16 + 8];
    }
#pragma unroll
    for (int mt = 0; mt < 4; ++mt) {
        bf16x8 ah = zf, al = zf;
        if (q == 0) {
            ah = *(const bf16x8 *)&XT[(16 * mt + c) * 16];
            al = *(const bf16x8 *)&XT[(16 * mt + c) * 16 + 8];
        }
        f32x4 g = {0.f, 0.f, 0.f, 0.f};
        g = MFMA16(ah, bh, g);
        g = MFMA16(al, bh, g);
        g = MFMA16(ah, bl, g);
        unsigned short *ph = &WT[(16 * w + c) * 136 + 16 * mt + 4 * q];
        unsigned short *pl = ph + 64;
        bf16x4 oh = *(bf16x4 *)ph, ol = *(bf16x4 *)pl;
        bf16x4 nh, nl;
#pragma unroll
        for (int r = 0; r < 4; ++r) {
            float wv = bf2f(oh[r]) + bf2f(ol[r]) - LR * g[r];
            short hh, ll;
            cvt1(wv, hh, ll);
            nh[r] = hh; nl[r] = ll;
            if (WR) {
                WR[(16 * mt + 4 * q + r) * 136 + 16 * w + c] = (unsigned short)hh;
                WR[(16 * mt + 4 * q + r) * 136 + 64 + 16 * w + c] = (unsigned short)ll;
            }
        }
        *(bf16x4 *)ph = nh;
        *(bf16x4 *)pl = nl;
    }
}

// ---------------------------------------------------------------------------
// TTT scan kernel: one block (256 thr = 4 waves) per head
// ---------------------------------------------------------------------------
__global__ __launch_bounds__(256) void ttt_scan(
    const float *__restrict__ q_g, const float *__restrict__ k_g,
    const float *__restrict__ v_g, float *__restrict__ out_g,
    const float *__restrict__ fw_w1, const float *__restrict__ fw_b1,
    const float *__restrict__ fw_w2, const float *__restrict__ fw_b2,
    const float *__restrict__ fw_lng, const float *__restrict__ fw_lnb,
    const float *__restrict__ loss_w, const float *__restrict__ loss_bv,
    const float *__restrict__ ttt_gv, const float *__restrict__ ttt_bv) {
    extern __shared__ char smem[];
    unsigned short *us = (unsigned short *)smem;
    float *fs = (float *)smem;

    unsigned short *W1T = us + U_W1T, *W2T = us + U_W2T, *W2R = us + U_W2R;
    unsigned short *LwT = us + U_LwT, *LwR = us + U_LwR;
    unsigned short *Kp = us + U_K, *Hp = us + U_H, *Zp = us + U_Z;
    unsigned short *DPp = us + U_DP, *DOp = us + U_DO;
    unsigned short *KT = us + U_KT, *HT = us + U_HT;
    unsigned short *DOT = us + U_DOT, *DAT = us + U_DAT;
    float *o_s = fs + F_O, *xh_s = fs + F_XH, *gd_s = fs + F_GD;
    float *tg_s = fs + F_TG;
    float *b1_s = fs + F_B1, *b2_s = fs + F_B2, *lg_s = fs + F_LG;
    float *lb_s = fs + F_LB, *Lb_s = fs + F_LBV;
    float *tG_s = fs + F_TGm, *tB_s = fs + F_TBm, *rstd_s = fs + F_RSTD;

    const int h = blockIdx.x, tid = threadIdx.x;
    const int w = tid >> 6, lane = tid & 63, c = lane & 15, q = lane >> 4;

    // ---- init: split weights into bf16 hi/lo planes
    for (int i = tid; i < 4096; i += 256) {
        int r = i >> 6, cc = i & 63;
        short hi, lo;
        cvt1(fw_w1[h * 4096 + i], hi, lo);           // [d=r][f=cc]
        W1T[cc * 136 + r] = (unsigned short)hi;
        W1T[cc * 136 + 64 + r] = (unsigned short)lo;
        cvt1(fw_w2[h * 4096 + i], hi, lo);           // [f=r][d=cc]
        W2T[cc * 136 + r] = (unsigned short)hi;
        W2T[cc * 136 + 64 + r] = (unsigned short)lo;
        W2R[r * 136 + cc] = (unsigned short)hi;
        W2R[r * 136 + 64 + cc] = (unsigned short)lo;
        cvt1(loss_w[i], hi, lo);                     // [d=r][e=cc]
        LwT[cc * 136 + r] = (unsigned short)hi;
        LwT[cc * 136 + 64 + r] = (unsigned short)lo;
        LwR[r * 136 + cc] = (unsigned short)hi;
        LwR[r * 136 + 64 + cc] = (unsigned short)lo;
    }
    // zero pad rows 8..15 of the 5 activation row-plane arrays
    for (int i = tid; i < 5 * 8 * 128; i += 256) {
        int a = i / 128, u = i % 128;
        int arr = a >> 3, row = 8 + (a & 7);
        unsigned short *base = (arr == 0) ? Kp : (arr == 1) ? Hp
                              : (arr == 2) ? Zp : (arr == 3) ? DPp : DOp;
        base[row * 136 + u] = 0;
    }
    __syncthreads();
    if (tid < 64) {
        b1_s[tid] = fw_b1[h * 64 + tid];
        b2_s[tid] = fw_b2[h * 64 + tid];
        lg_s[tid] = fw_lng[h * 64 + tid];
        lb_s[tid] = fw_lnb[h * 64 + tid];
        Lb_s[tid] = loss_bv[tid];
        tG_s[tid] = ttt_gv[h * 64 + tid];
        tB_s[tid] = ttt_bv[h * 64 + tid];
    }
    __syncthreads();

    const int bb = tid >> 5, j0 = (tid & 31) * 2;

    // prefetch token 0
    float2 pk, pv, pq;
    {
        int idx = ((bb * Sv + 0) * Hv + h) * Dv + j0;
        pk = *(const float2 *)&k_g[idx];
        pv = *(const float2 *)&v_g[idx];
        pq = *(const float2 *)&q_g[idx];
    }

#pragma unroll 1
    for (int t = 0; t < Sv; ++t) {
        // ---- prologue: stage k (planes + kT), tg
        {
            short h0, l0, h1, l1;
            cvt1(pk.x, h0, l0);
            cvt1(pk.y, h1, l1);
            *(unsigned *)&Kp[bb * 136 + j0] = pack2(h0, h1);
            *(unsigned *)&Kp[bb * 136 + 64 + j0] = pack2(l0, l1);
            KT[j0 * 16 + bb] = (unsigned short)h0;
            KT[j0 * 16 + 8 + bb] = (unsigned short)l0;
            KT[(j0 + 1) * 16 + bb] = (unsigned short)h1;
            KT[(j0 + 1) * 16 + 8 + bb] = (unsigned short)l1;
            tg_s[bb * 68 + j0] = pv.x - pk.x;
            tg_s[bb * 68 + j0 + 1] = pv.y - pk.y;
        }
        __syncthreads();

#pragma unroll 1
        for (int step = 0; step < 4; ++step) {
            // F1: h = gelu(k@W1 + b1)
            f32x4 acc = mm64(Kp, W1T, w, c, q);
            if (q < 2) {
                float bias = b1_s[16 * w + c];
                bf16x4 hs, ls;
#pragma unroll
                for (int r = 0; r < 4; ++r) {
                    float g, dg;
                    gelu_both(acc[r] + bias, g, dg);
                    int row = 4 * q + r;
                    short hh, ll;
                    cvt1(g, hh, ll);
                    Hp[row * 136 + 16 * w + c] = (unsigned short)hh;
                    Hp[row * 136 + 64 + 16 * w + c] = (unsigned short)ll;
                    hs[r] = hh; ls[r] = ll;
                    gd_s[row * 68 + 16 * w + c] = dg;
                }
                *(bf16x4 *)&HT[(16 * w + c) * 16 + 4 * q] = hs;
                *(bf16x4 *)&HT[(16 * w + c) * 16 + 8 + 4 * q] = ls;
            }
            __syncthreads();
            // F2: o = h@W2 + b2
            acc = mm64(Hp, W2T, w, c, q);
            if (q < 2) {
                float bias = b2_s[16 * w + c];
#pragma unroll
                for (int r = 0; r < 4; ++r)
                    o_s[(4 * q + r) * 68 + 16 * w + c] = acc[r] + bias;
            }
            __syncthreads();
            // LN fwd (thread-mapped); xh kept in regs for LNb
            float xh0_r, xh1_r;
            {
                float x0 = o_s[bb * 68 + j0], x1 = o_s[bb * 68 + j0 + 1];
                float mu = red32(x0 + x1) * (1.f / 64.f);
                float d0 = x0 - mu, d1 = x1 - mu;
                float var = red32(d0 * d0 + d1 * d1) * (1.f / 64.f);
                float rs = rsqrtf(var + 1e-5f);
                float xh0 = d0 * rs, xh1 = d1 * rs;
                xh_s[bb * 68 + j0] = xh0;
                xh_s[bb * 68 + j0 + 1] = xh1;
                float z0 = xh0 * lg_s[j0] + lb_s[j0];
                float z1 = xh1 * lg_s[j0 + 1] + lb_s[j0 + 1];
                short h0, l0, h1, l1;
                cvt1(z0, h0, l0);
                cvt1(z1, h1, l1);
                *(unsigned *)&Zp[bb * 136 + j0] = pack2(h0, h1);
                *(unsigned *)&Zp[bb * 136 + 64 + j0] = pack2(l0, l1);
                if ((tid & 31) == 0) rstd_s[bb] = rs;
                xh0_r = xh0; xh1_r = xh1;
            }
            __syncthreads();
            // F3: dpred = (z@Lw + Lb - tg) * SCALE
            acc = mm64(Zp, LwT, w, c, q);
            if (q < 2) {
                int col = 16 * w + c;
#pragma unroll
                for (int r = 0; r < 4; ++r) {
                    int row = 4 * q + r;
                    float dp = (acc[r] + Lb_s[col] - tg_s[row * 68 + col]) * SCALE;
                    short hh, ll;
                    cvt1(dp, hh, ll);
                    DPp[row * 136 + col] = (unsigned short)hh;
                    DPp[row * 136 + 64 + col] = (unsigned short)ll;
                }
            }
            __syncthreads();
            // B1: dz = dp @ Lw^T  (into o_s, reused as dz buffer)
            acc = mm64(DPp, LwR, w, c, q);
            if (q < 2) {
#pragma unroll
                for (int r = 0; r < 4; ++r)
                    o_s[(4 * q + r) * 68 + 16 * w + c] = acc[r];
            }
            __syncthreads();
            // LN bwd (thread-mapped) -> do planes + doT
            {
                float dz0 = o_s[bb * 68 + j0], dz1 = o_s[bb * 68 + j0 + 1];
                float dxh0 = dz0 * lg_s[j0], dxh1 = dz1 * lg_s[j0 + 1];
                float S1 = red32(dxh0 + dxh1) * (1.f / 64.f);
                float S2 = red32(dxh0 * xh0_r + dxh1 * xh1_r) * (1.f / 64.f);
                float rs = rstd_s[bb];
                float do0 = rs * (dxh0 - S1 - xh0_r * S2);
                float do1 = rs * (dxh1 - S1 - xh1_r * S2);
                short h0, l0, h1, l1;
                cvt1(do0, h0, l0);
                cvt1(do1, h1, l1);
                *(unsigned *)&DOp[bb * 136 + j0] = pack2(h0, h1);
                *(unsigned *)&DOp[bb * 136 + 64 + j0] = pack2(l0, l1);
                DOT[j0 * 16 + bb] = (unsigned short)h0;
                DOT[j0 * 16 + 8 + bb] = (unsigned short)l0;
                DOT[(j0 + 1) * 16 + bb] = (unsigned short)h1;
                DOT[(j0 + 1) * 16 + 8 + bb] = (unsigned short)l1;
            }
            __syncthreads();
            // B2: dh = do @ W2^T ; da = dh * gelu' -> DAT
            acc = mm64(DOp, W2R, w, c, q);
            if (q < 2) {
                bf16x4 hs, ls;
#pragma unroll
                for (int r = 0; r < 4; ++r) {
                    int b = 4 * q + r;
                    float da = acc[r] * gd_s[b * 68 + 16 * w + c];
                    short hh, ll;
                    cvt1(da, hh, ll);
                    hs[r] = hh; ls[r] = ll;
                }
                *(bf16x4 *)&DAT[(16 * w + c) * 16 + 4 * q] = hs;
                *(bf16x4 *)&DAT[(16 * w + c) * 16 + 8 + 4 * q] = ls;
            }
            __syncthreads();
            // update: W1 -= LR*k^T@da ; W2 -= LR*h^T@do ; vector params
            updW(KT, DAT, W1T, nullptr, w, c, q);
            updW(HT, DOT, W2T, W2R, w, c, q);
            if (tid < 64) {
                bf16x8 dh_ = *(const bf16x8 *)&DAT[tid * 16];
                bf16x8 dl_ = *(const bf16x8 *)&DAT[tid * 16 + 8];
                bf16x8 oh_ = *(const bf16x8 *)&DOT[tid * 16];
                bf16x8 ol_ = *(const bf16x8 *)&DOT[tid * 16 + 8];
                float db1 = 0.f, db2 = 0.f, dlb = 0.f, dlg = 0.f;
#pragma unroll
                for (int j = 0; j < 8; ++j) {
                    db1 += bf2f(dh_[j]) + bf2f(dl_[j]);
                    db2 += bf2f(oh_[j]) + bf2f(ol_[j]);
                }
#pragma unroll
                for (int b = 0; b < 8; ++b) {
                    float dzv = o_s[b * 68 + tid];
                    dlb += dzv;
                    dlg += dzv * xh_s[b * 68 + tid];
                }
                lb_s[tid] -= LR * dlb;
                lg_s[tid] -= LR * dlg;
                b1_s[tid] -= LR * db1;
                b2_s[tid] -= LR * db2;
            }
            __syncthreads();
        }

        // ---- final forward with updated params
        f32x4 acc = mm64(Kp, W1T, w, c, q);
        if (q < 2) {
            float bias = b1_s[16 * w + c];
#pragma unroll
            for (int r = 0; r < 4; ++r) {
                float g = gelu_f(acc[r] + bias);
                int row = 4 * q + r;
                short hh, ll;
                cvt1(g, hh, ll);
                Hp[row * 136 + 16 * w + c] = (unsigned short)hh;
                Hp[row * 136 + 64 + 16 * w + c] = (unsigned short)ll;
            }
        }
        __syncthreads();
        acc = mm64(Hp, W2T, w, c, q);
        if (q < 2) {
            float bias = b2_s[16 * w + c];
#pragma unroll
            for (int r = 0; r < 4; ++r)
                o_s[(4 * q + r) * 68 + 16 * w + c] = acc[r] + bias;
        }
        __syncthreads();
        // epilogue: LN(lg,lb) -> LN(ttt_g,ttt_b) -> out = q + z2 ; prefetch t+1
        {
            float x0 = o_s[bb * 68 + j0], x1 = o_s[bb * 68 + j0 + 1];
            float mu = red32(x0 + x1) * (1.f / 64.f);
            float d0 = x0 - mu, d1 = x1 - mu;
            float var = red32(d0 * d0 + d1 * d1) * (1.f / 64.f);
            float rs = rsqrtf(var + 1e-5f);
            float z0 = d0 * rs * lg_s[j0] + lb_s[j0];
            float z1 = d1 * rs * lg_s[j0 + 1] + lb_s[j0 + 1];
            float mu2 = red32(z0 + z1) * (1.f / 64.f);
            float e0 = z0 - mu2, e1 = z1 - mu2;
            float var2 = red32(e0 * e0 + e1 * e1) * (1.f / 64.f);
            float rs2 = rsqrtf(var2 + 1e-5f);
            float z20 = e0 * rs2 * tG_s[j0] + tB_s[j0];
            float z21 = e1 * rs2 * tG_s[j0 + 1] + tB_s[j0 + 1];
            int idx = ((bb * Sv + t) * Hv + h) * Dv + j0;
            float2 ov;
            ov.x = pq.x + z20;
            ov.y = pq.y + z21;
            *(float2 *)&out_g[idx] = ov;
            if (t + 1 < Sv) {
                int idx2 = ((bb * Sv + t + 1) * Hv + h) * Dv + j0;
                pk = *(const float2 *)&k_g[idx2];
                pv = *(const float2 *)&v_g[idx2];
                pq = *(const float2 *)&q_g[idx2];
            }
        }
        // no barrier needed here: prologue writes (Kp/KT/tg) have no readers
        // still in flight (all waves passed the F1/F3/upd barriers of token t)
    }
}

// ---------------------------------------------------------------------------
// fp32 GEMM: C[M,N] = A[M,K] @ B[K,N]; mode 1: C = gelu(acc) * gate_ln
// ---------------------------------------------------------------------------
__global__ __launch_bounds__(256) void gemm_f32(
    const float *__restrict__ A, const float *__restrict__ B,
    float *__restrict__ C, const float *__restrict__ gate_ln,
    int M, int N, int K, int mode) {
    __shared__ float As[16][68];
    __shared__ float Bs[16][64];
    const int tid = threadIdx.x;
    const int tx = tid & 15, ty = tid >> 4;
    const int bm = blockIdx.y * 64, bn = blockIdx.x * 64;

    float acc[4][4] = {};
    for (int k0 = 0; k0 < K; k0 += 16) {
        {
            int r = tid >> 2, kk = (tid & 3) * 4;
            float4 av = *(const float4 *)(A + (long)(bm + r) * K + k0 + kk);
            As[kk + 0][r] = av.x;
            As[kk + 1][r] = av.y;
            As[kk + 2][r] = av.z;
            As[kk + 3][r] = av.w;
            int rr = tid >> 4, cc = (tid & 15) * 4;
            float4 bv = *(const float4 *)(B + (long)(k0 + rr) * N + bn + cc);
            *(float4 *)&Bs[rr][cc] = bv;
        }
        __syncthreads();
#pragma unroll
        for (int kk = 0; kk < 16; ++kk) {
            float4 a4 = *(float4 *)&As[kk][ty * 4];
            float4 b4 = *(float4 *)&Bs[kk][tx * 4];
            float a[4] = {a4.x, a4.y, a4.z, a4.w};
            float b[4] = {b4.x, b4.y, b4.z, b4.w};
#pragma unroll
            for (int i = 0; i < 4; ++i)
#pragma unroll
                for (int j = 0; j < 4; ++j) acc[i][j] += a[i] * b[j];
        }
        __syncthreads();
    }
#pragma unroll
    for (int i = 0; i < 4; ++i) {
        int row = bm + ty * 4 + i;
        float4 out;
        float v[4];
#pragma unroll
        for (int j = 0; j < 4; ++j) {
            float val = acc[i][j];
            if (mode == 1) {
                int col = bn + tx * 4 + j;
                val = gelu_f(val) * gate_ln[(long)row * N + col];
            }
            v[j] = val;
        }
        out.x = v[0]; out.y = v[1]; out.z = v[2]; out.w = v[3];
        *(float4 *)(C + (long)row * N + bn + tx * 4) = out;
    }
}

// ---------------------------------------------------------------------------
// Row LayerNorm over 1024 (post-scan, pn_g / pn_b)
// ---------------------------------------------------------------------------
__global__ __launch_bounds__(256) void row_ln(const float *__restrict__ in,
                                              float *__restrict__ out,
                                              const float *__restrict__ g,
                                              const float *__restrict__ b) {
    __shared__ float sred[4], s2red[4];
    const int row = blockIdx.x;
    const int tid = threadIdx.x;
    const float *x = in + (long)row * 1024;
    float4 v = *(const float4 *)(x + tid * 4);
    float s = v.x + v.y + v.z + v.w;
    float s2 = v.x * v.x + v.y * v.y + v.z * v.z + v.w * v.w;
#pragma unroll
    for (int m = 1; m <= 32; m <<= 1) {
        s += __shfl_xor(s, m);
        s2 += __shfl_xor(s2, m);
    }
    if ((tid & 63) == 0) {
        sred[tid >> 6] = s;
        s2red[tid >> 6] = s2;
    }
    __syncthreads();
    float S = sred[0] + sred[1] + sred[2] + sred[3];
    float S2 = s2red[0] + s2red[1] + s2red[2] + s2red[3];
    float mu = S * (1.f / 1024.f);
    float var = S2 * (1.f / 1024.f) - mu * mu;
    float rs = rsqrtf(var + 1e-5f);
    float o[4] = {v.x, v.y, v.z, v.w};
    float4 ov;
    float r[4];
#pragma unroll
    for (int i = 0; i < 4; ++i) {
        int col = tid * 4 + i;
        r[i] = (o[i] - mu) * rs * g[col] + b[col];
    }
    ov.x = r[0]; ov.y = r[1]; ov.z = r[2]; ov.w = r[3];
    *(float4 *)(out + (long)row * 1024 + tid * 4) = ov;
}

// ---------------------------------------------------------------------------
// Launch
// ---------------------------------------------------------------------------
extern "C" void kernel_launch(void *const *d_in, const int *in_sizes, int n_in,
                              void *d_out, int out_size, void *d_ws,
                              size_t ws_size, hipStream_t stream) {
    const float *x = (const float *)d_in[0];
    const float *wq = (const float *)d_in[1];
    const float *wk = (const float *)d_in[2];
    const float *wv = (const float *)d_in[3];
    const float *fw_w1 = (const float *)d_in[4];
    const float *fw_b1 = (const float *)d_in[5];
    const float *fw_w2 = (const float *)d_in[6];
    const float *fw_b2 = (const float *)d_in[7];
    const float *fw_lng = (const float *)d_in[8];
    const float *fw_lnb = (const float *)d_in[9];
    const float *loss_w = (const float *)d_in[10];
    const float *loss_b = (const float *)d_in[11];
    const float *ttt_g = (const float *)d_in[12];
    const float *ttt_b = (const float *)d_in[13];
    const float *wo = (const float *)d_in[14];
    const float *wg = (const float *)d_in[15];
    const float *pn_g = (const float *)d_in[16];
    const float *pn_b = (const float *)d_in[17];

    const long MAT = 2048L * 1024L;
    float *q_ws = (float *)d_ws;
    float *k_ws = q_ws + MAT;
    float *v_ws = k_ws + MAT;
    float *out_ws = v_ws + MAT;
    float *ln_ws = k_ws;       // reuse (k dead after scan)
    float *gated_ws = v_ws;    // reuse (v dead after scan)

    dim3 gg(1024 / 64, 2048 / 64), bt(256);
    hipLaunchKernelGGL(gemm_f32, gg, bt, 0, stream, x, wq, q_ws,
                       (const float *)nullptr, 2048, 1024, 1024, 0);
    hipLaunchKernelGGL(gemm_f32, gg, bt, 0, stream, x, wk, k_ws,
                       (const float *)nullptr, 2048, 1024, 1024, 0);
    hipLaunchKernelGGL(gemm_f32, gg, bt, 0, stream, x, wv, v_ws,
                       (const float *)nullptr, 2048, 1024, 1024, 0);

    (void)hipFuncSetAttribute((const void *)ttt_scan,
                              hipFuncAttributeMaxDynamicSharedMemorySize,
                              LDS_BYTES);
    hipLaunchKernelGGL(ttt_scan, dim3(16), dim3(256), LDS_BYTES, stream,
                       q_ws, k_ws, v_ws, out_ws, fw_w1, fw_b1, fw_w2, fw_b2,
                       fw_lng, fw_lnb, loss_w, loss_b, ttt_g, ttt_b);

    hipLaunchKernelGGL(row_ln, dim3(2048), dim3(256), 0, stream, out_ws, ln_ws,
                       pn_g, pn_b);
    hipLaunchKernelGGL(gemm_f32, gg, bt, 0, stream, x, wg, gated_ws, ln_ws,
                       2048, 1024, 1024, 1);
    hipLaunchKernelGGL(gemm_f32, gg, bt, 0, stream, gated_ws, wo,
                       (float *)d_out, (const float *)nullptr, 2048, 1024,
                       1024, 0);
}